// Round 4
// baseline (1996.987 us; speedup 1.0000x reference)
//
#include <hip/hip_runtime.h>
#include <math.h>

#define HID 128

typedef __attribute__((ext_vector_type(8))) short short8;
typedef __attribute__((ext_vector_type(4))) float f32x4;

__device__ __forceinline__ float bf2f(unsigned int u16) {
  union { unsigned int i; float f; } x; x.i = u16 << 16; return x.f;
}
__device__ __forceinline__ unsigned short f2bf(float f) {
  union { float f; unsigned int i; } x; x.f = f;
  unsigned int i = x.i;
  unsigned int r = i + 0x7FFFu + ((i >> 16) & 1u);
  return (unsigned short)(r >> 16);
}

// ---------------- weight convert: BT[l][n][k] = W[l][k][n] (bf16), biascat ----
__global__ __launch_bounds__(128) void wcvt_kernel(
    const float* __restrict__ Wq, const float* __restrict__ bq,
    const float* __restrict__ Wk, const float* __restrict__ bk,
    const float* __restrict__ Wv, const float* __restrict__ bv,
    const float* __restrict__ Ws, const float* __restrict__ bs,
    unsigned short* __restrict__ BT, float* __restrict__ biascat)
{
  int id = blockIdx.x;
  int l = id / 1664;
  int n = id - l * 1664;
  int k = threadIdx.x;
  const float* W; const float* bias; int nl, ldb;
  if (n < 512)       { W = Wq + (size_t)l * 65536; bias = bq + (size_t)l * 512; nl = n;        ldb = 512; }
  else if (n < 1024) { W = Wk + (size_t)l * 65536; bias = bk + (size_t)l * 512; nl = n - 512;  ldb = 512; }
  else if (n < 1536) { W = Wv + (size_t)l * 65536; bias = bv + (size_t)l * 512; nl = n - 1024; ldb = 512; }
  else               { W = Ws + (size_t)l * 16384; bias = bs + (size_t)l * 128; nl = n - 1536; ldb = 128; }
  BT[((size_t)l * 1664 + n) * 128 + k] = f2bf(W[(size_t)k * ldb + nl]);
  if (k == 0) biascat[(size_t)l * 1664 + n] = bias[nl];
}

// ---------------- lin0: h = x @ W(70x128) + b  (fp32 + bf16 copy) ------------
__global__ __launch_bounds__(128) void lin0_kernel(
    const float* __restrict__ x, const float* __restrict__ W,
    const float* __restrict__ b, float* __restrict__ h,
    unsigned short* __restrict__ hb, int N, int inF)
{
  __shared__ float xs[128];
  int n = blockIdx.x;
  int t = threadIdx.x;
  if (t < inF) xs[t] = x[(size_t)n * inF + t];
  __syncthreads();
  float acc = b[t];
  for (int k = 0; k < inF; k++) acc += xs[k] * W[(size_t)k * 128 + t];
  h[(size_t)n * 128 + t] = acc;
  hb[(size_t)n * 128 + t] = f2bf(acc);
}

// ---------------- MFMA projection GEMM (row-stationary) ----------------
// C[M,1664] = A[M,128](bf16) @ BT^T.  One block per 128 rows; A tile staged to
// LDS once; loop over 13 column-chunks of 128 (each entirely within one
// region: 0..3=q, 4..7=k, 8..11=v, 12=skip).  XOR-swizzled LDS chunk layout:
// element chunk j (16B) of row r lives at position j^(r&15) -> conflict-free
// fragment reads while global_load_lds staging stays linear on the LDS side.
__global__ __launch_bounds__(256) void proj_mfma_kernel(
    const unsigned short* __restrict__ A, const unsigned short* __restrict__ BT,
    const float* __restrict__ bias, int M,
    unsigned short* __restrict__ qo, unsigned short* __restrict__ ko,
    unsigned short* __restrict__ vo, float* __restrict__ hn)
{
  __shared__ unsigned short lsA[128 * 128];
  __shared__ unsigned short lsB[128 * 128];
  const int t = threadIdx.x;
  const int wv = t >> 6, ln = t & 63;
  const int wx = wv & 1, wy = wv >> 1;
  const int m0 = blockIdx.x * 128;

  // ---- stage A tile once: 2048 chunks of 16B, swizzled source ----
#pragma unroll
  for (int it = 0; it < 8; it++) {
    const int c = it * 256 + t;            // LDS chunk position (linear)
    const int r = c >> 4;
    const int p = c & 15;
    const int jsrc = p ^ (r & 15);         // source k-chunk
    int gr = m0 + r; if (gr >= M) gr = M - 1;
    const unsigned short* gA = A + (size_t)gr * 128 + jsrc * 8;
    __builtin_amdgcn_global_load_lds(
        (const __attribute__((address_space(1))) void*)gA,
        (__attribute__((address_space(3))) void*)((char*)lsA + c * 16), 16, 0, 0);
  }

  const int fr = ln & 15;
  const int quad = ln >> 4;                // 0..3
  const int rbase = quad * 4;
  const int cl = ln & 15;

  for (int nc = 0; nc < 13; nc++) {
    __syncthreads();                       // prev chunk's ds_reads done
#pragma unroll
    for (int it = 0; it < 8; it++) {
      const int c = it * 256 + t;
      const int r = c >> 4;
      const int p = c & 15;
      const int jsrc = p ^ (r & 15);
      const unsigned short* gB = BT + (size_t)(nc * 128 + r) * 128 + jsrc * 8;
      __builtin_amdgcn_global_load_lds(
          (const __attribute__((address_space(1))) void*)gB,
          (__attribute__((address_space(3))) void*)((char*)lsB + c * 16), 16, 0, 0);
    }
    __syncthreads();                       // staging (A on first iter too) done

    f32x4 acc[4][4];
#pragma unroll
    for (int i = 0; i < 4; i++)
#pragma unroll
      for (int j = 0; j < 4; j++) acc[i][j] = (f32x4){0.f, 0.f, 0.f, 0.f};

#pragma unroll
    for (int kb = 0; kb < 4; kb++) {
      const int J = kb * 4 + quad;         // k-chunk index 0..15
      short8 af[4], bf[4];
#pragma unroll
      for (int i = 0; i < 4; i++) {
        const int R = wy * 64 + i * 16 + fr;
        af[i] = *(const short8*)(&lsA[(R * 16 + (J ^ (R & 15))) * 8]);
      }
#pragma unroll
      for (int j = 0; j < 4; j++) {
        const int R = wx * 64 + j * 16 + fr;
        bf[j] = *(const short8*)(&lsB[(R * 16 + (J ^ (R & 15))) * 8]);
      }
#pragma unroll
      for (int i = 0; i < 4; i++)
#pragma unroll
        for (int j = 0; j < 4; j++)
          acc[i][j] = __builtin_amdgcn_mfma_f32_16x16x32_bf16(af[i], bf[j], acc[i][j], 0, 0, 0);
    }

    // ---- epilogue for this column chunk ----
    const int region = nc >> 2;            // 0=q 1=k 2=v 3=skip
    unsigned short* out16 = (region == 0) ? qo : (region == 1) ? ko : vo;
#pragma unroll
    for (int j = 0; j < 4; j++) {
      const int colg = nc * 128 + wx * 64 + j * 16 + cl;
      const float bv = bias[colg];
      const int col = colg - region * 512;
#pragma unroll
      for (int i = 0; i < 4; i++) {
        f32x4 c = acc[i][j];
#pragma unroll
        for (int r = 0; r < 4; r++) {
          const int row = m0 + wy * 64 + i * 16 + rbase + r;
          if (row < M) {
            float val = c[r] + bv;
            if (region < 3) out16[(size_t)row * 512 + col] = f2bf(val);
            else            hn[(size_t)row * 128 + col] = val;
          }
        }
      }
    }
  }
}

// ---------------- CSR build ----------------
__global__ __launch_bounds__(256) void hist_kernel(
    const int* __restrict__ dst, int* __restrict__ deg, int E)
{
  int e = blockIdx.x * 256 + threadIdx.x;
  if (e < E) atomicAdd(&deg[dst[e]], 1);
}

__global__ __launch_bounds__(256) void scan_block_kernel(
    const int* __restrict__ in, int* __restrict__ out, int* __restrict__ bsums, int N)
{
  __shared__ int sm[256];
  int i = blockIdx.x * 256 + threadIdx.x;
  int v = (i < N) ? in[i] : 0;
  sm[threadIdx.x] = v; __syncthreads();
  for (int off = 1; off < 256; off <<= 1) {
    int t = (threadIdx.x >= off) ? sm[threadIdx.x - off] : 0;
    __syncthreads();
    sm[threadIdx.x] += t;
    __syncthreads();
  }
  if (i < N) out[i] = sm[threadIdx.x] - v;   // exclusive
  if (threadIdx.x == 255 && bsums) bsums[blockIdx.x] = sm[255];
}

__global__ __launch_bounds__(256) void scan_finish_kernel(
    int* __restrict__ row_start, int* __restrict__ cursor,
    const int* __restrict__ bsums_scan, int N, int E)
{
  int i = blockIdx.x * 256 + threadIdx.x;
  if (i < N) {
    int val = row_start[i] + bsums_scan[blockIdx.x];
    row_start[i] = val;
    cursor[i] = val;
  }
  if (i == 0) row_start[N] = E;
}

__global__ __launch_bounds__(256) void scatter_kernel(
    const int* __restrict__ src, const int* __restrict__ dst,
    int* __restrict__ cursor, int* __restrict__ csr_src, int E)
{
  int e = blockIdx.x * 256 + threadIdx.x;
  if (e < E) {
    int pos = atomicAdd(&cursor[dst[e]], 1);
    csr_src[pos] = src[e];
  }
}

// ---------------- fused per-node attention (one wave per dst node) ----------
// h[d] = relu(h[d] + mean_h( softmax_e * v[src_e,h,:] ));  hb = bf16(h)
// Depth-2 software pipeline over edge pairs (4 gathers in flight).
__global__ __launch_bounds__(256) void node_attn_kernel(
    const unsigned short* __restrict__ q, const unsigned short* __restrict__ k,
    const unsigned short* __restrict__ v,
    const int* __restrict__ row_start, const int* __restrict__ csr_src,
    float* __restrict__ hn, unsigned short* __restrict__ hb, int N)
{
  int d = (blockIdx.x * 256 + threadIdx.x) >> 6;
  int lane = threadIdx.x & 63;
  if (d >= N) return;
  int beg = row_start[d], end = row_start[d + 1];

  const uint4 qv = *(const uint4*)(q + (size_t)d * 512 + lane * 8);
  float q0 = bf2f(qv.x & 0xFFFFu), q1 = bf2f(qv.x >> 16);
  float q2 = bf2f(qv.y & 0xFFFFu), q3 = bf2f(qv.y >> 16);
  float q4 = bf2f(qv.z & 0xFFFFu), q5 = bf2f(qv.z >> 16);
  float q6 = bf2f(qv.w & 0xFFFFu), q7 = bf2f(qv.w >> 16);

  float num[8] = {0.f,0.f,0.f,0.f,0.f,0.f,0.f,0.f};
  float den = 0.f;

  auto krow = [&](int s) { return *(const uint4*)(k + (size_t)s * 512 + lane * 8); };
  auto vrow = [&](int s) { return *(const uint4*)(v + (size_t)s * 512 + lane * 8); };
  auto accum = [&](const uint4& kv, const uint4& vv) {
    float p = q0 * bf2f(kv.x & 0xFFFFu) + q1 * bf2f(kv.x >> 16)
            + q2 * bf2f(kv.y & 0xFFFFu) + q3 * bf2f(kv.y >> 16)
            + q4 * bf2f(kv.z & 0xFFFFu) + q5 * bf2f(kv.z >> 16)
            + q6 * bf2f(kv.w & 0xFFFFu) + q7 * bf2f(kv.w >> 16);
    p += __shfl_xor(p, 1);
    p += __shfl_xor(p, 2);
    p += __shfl_xor(p, 4);
    p += __shfl_xor(p, 8);
    float e = __expf(p * 0.08838834764831845f);  // 1/sqrt(128)
    den += e;
    num[0] += e * bf2f(vv.x & 0xFFFFu); num[1] += e * bf2f(vv.x >> 16);
    num[2] += e * bf2f(vv.y & 0xFFFFu); num[3] += e * bf2f(vv.y >> 16);
    num[4] += e * bf2f(vv.z & 0xFFFFu); num[5] += e * bf2f(vv.z >> 16);
    num[6] += e * bf2f(vv.w & 0xFFFFu); num[7] += e * bf2f(vv.w >> 16);
  };

  if (beg < end) {
    const int last = end - 1;
    int sA = csr_src[beg];
    int sB = csr_src[min(beg + 1, last)];
    uint4 kA = krow(sA), vA = vrow(sA);
    uint4 kB = krow(sB), vB = vrow(sB);
    for (int i = beg; i < end; i += 2) {
      int sC = csr_src[min(i + 2, last)];
      int sD = csr_src[min(i + 3, last)];
      uint4 kC = krow(sC), vC = vrow(sC);
      uint4 kD = krow(sD), vD = vrow(sD);
      accum(kA, vA);
      if (i + 1 < end) accum(kB, vB);
      kA = kC; vA = vC; kB = kD; vB = vD;
    }
  }

  float inv = (den > 0.f) ? 0.25f / den : 0.f;
#pragma unroll
  for (int j = 0; j < 8; j++) {
    float r = num[j] * inv;
    r += __shfl_xor(r, 16);   // combine 4 heads
    r += __shfl_xor(r, 32);
    num[j] = r;
  }
  if (lane < 16) {
    float* hp = hn + (size_t)d * 128 + lane * 8;
    float4 o0 = *(const float4*)(hp);
    float4 o1 = *(const float4*)(hp + 4);
    o0.x = fmaxf(o0.x + num[0], 0.f);
    o0.y = fmaxf(o0.y + num[1], 0.f);
    o0.z = fmaxf(o0.z + num[2], 0.f);
    o0.w = fmaxf(o0.w + num[3], 0.f);
    o1.x = fmaxf(o1.x + num[4], 0.f);
    o1.y = fmaxf(o1.y + num[5], 0.f);
    o1.z = fmaxf(o1.z + num[6], 0.f);
    o1.w = fmaxf(o1.w + num[7], 0.f);
    *(float4*)(hp) = o0;
    *(float4*)(hp + 4) = o1;
    uint4 hv;
    hv.x = (unsigned int)f2bf(o0.x) | ((unsigned int)f2bf(o0.y) << 16);
    hv.y = (unsigned int)f2bf(o0.z) | ((unsigned int)f2bf(o0.w) << 16);
    hv.z = (unsigned int)f2bf(o1.x) | ((unsigned int)f2bf(o1.y) << 16);
    hv.w = (unsigned int)f2bf(o1.z) | ((unsigned int)f2bf(o1.w) << 16);
    *(uint4*)(hb + (size_t)d * 128 + lane * 8) = hv;
  }
}

// ---------------- pooling: emb[batch[n]] += h[n] (batch sorted) ----------------
__global__ __launch_bounds__(128) void pool_kernel(
    const float* __restrict__ h, const int* __restrict__ batch,
    float* __restrict__ emb, int N)
{
  int d = threadIdx.x;
  int n0 = blockIdx.x * 128;
  int n1 = min(n0 + 128, N);
  float acc = 0.f; int cur = -1;
  for (int n = n0; n < n1; n++) {
    int g = batch[n];
    if (g != cur) {
      if (cur >= 0) atomicAdd(&emb[(size_t)cur * 128 + d], acc);
      cur = g; acc = 0.f;
    }
    acc += h[(size_t)n * 128 + d];
  }
  if (cur >= 0) atomicAdd(&emb[(size_t)cur * 128 + d], acc);
}

// ---------------- final score ----------------
__global__ __launch_bounds__(128) void score_kernel(
    const float* __restrict__ hemb, const float* __restrict__ temb,
    const int* __restrict__ rels,
    const float* __restrict__ wqW, const float* __restrict__ wqb,
    const float* __restrict__ wkW, const float* __restrict__ wkb,
    const float* __restrict__ rel_emb, float* __restrict__ out)
{
  const int b = blockIdx.x, i = threadIdx.x;
  __shared__ float hs[128], ts[128], hnv[128], tnv[128], red[128];
  hs[i] = hemb[(size_t)b * 128 + i];
  ts[i] = temb[(size_t)b * 128 + i];
  __syncthreads();
  float qv = wqb[i], kv = wkb[i];
  for (int k = 0; k < 128; k++) {
    qv += hs[k] * wqW[k * 128 + i];
    kv += ts[k] * wkW[k * 128 + i];
  }
  float inter = tanhf(qv * kv);
  float hx = hs[i] + inter, tx2 = ts[i] + inter;

  red[i] = hx * hx; __syncthreads();
  for (int s = 64; s > 0; s >>= 1) { if (i < s) red[i] += red[i + s]; __syncthreads(); }
  float hnorm = fmaxf(sqrtf(red[0]), 1e-12f);
  __syncthreads();
  red[i] = tx2 * tx2; __syncthreads();
  for (int s = 64; s > 0; s >>= 1) { if (i < s) red[i] += red[i + s]; __syncthreads(); }
  float tnorm = fmaxf(sqrtf(red[0]), 1e-12f);
  __syncthreads();
  hnv[i] = hx / hnorm; tnv[i] = tx2 / tnorm;
  __syncthreads();

  const float* R = rel_emb + (size_t)rels[b] * 16384 + (size_t)i * 128;
  float dot = 0.f, nrm = 0.f;
  for (int j = 0; j < 128; j++) { float r = R[j]; dot += r * tnv[j]; nrm += r * r; }
  float contrib = hnv[i] * dot / fmaxf(sqrtf(nrm), 1e-12f);
  red[i] = contrib; __syncthreads();
  for (int s = 64; s > 0; s >>= 1) { if (i < s) red[i] += red[i + s]; __syncthreads(); }
  if (i == 0) out[b] = red[0];
}

extern "C" void kernel_launch(void* const* d_in, const int* in_sizes, int n_in,
                              void* d_out, int out_size, void* d_ws, size_t ws_size,
                              hipStream_t stream)
{
  const float* h_x     = (const float*)d_in[0];
  const int*   h_ei    = (const int*)d_in[1];
  const int*   h_batch = (const int*)d_in[2];
  const float* t_x     = (const float*)d_in[3];
  const int*   t_ei    = (const int*)d_in[4];
  const int*   t_batch = (const int*)d_in[5];
  const int*   rels    = (const int*)d_in[6];
  const float* lin0_W  = (const float*)d_in[7];
  const float* lin0_b  = (const float*)d_in[8];
  const float* Wq      = (const float*)d_in[9];
  const float* bq      = (const float*)d_in[10];
  const float* Wk      = (const float*)d_in[11];
  const float* bk      = (const float*)d_in[12];
  const float* Wv      = (const float*)d_in[13];
  const float* bv      = (const float*)d_in[14];
  const float* Ws      = (const float*)d_in[15];
  const float* bs      = (const float*)d_in[16];
  const float* wqW     = (const float*)d_in[17];
  const float* wqb     = (const float*)d_in[18];
  const float* wkW     = (const float*)d_in[19];
  const float* wkb     = (const float*)d_in[20];
  const float* rel_emb = (const float*)d_in[21];

  const int N = in_sizes[2];          // 50000
  const int E = in_sizes[1] / 2;      // 400000
  const int G = in_sizes[6];          // 512
  const int inF = in_sizes[7] / 128;  // 70

  char* ws = (char*)d_ws;
  size_t off = 0;
  auto alloc = [&](size_t bytes) -> void* {
    void* p = ws + off; off += (bytes + 255) & ~(size_t)255; return p;
  };
  float* hA            = (float*)alloc((size_t)N * 128 * 4);
  unsigned short* hbuf = (unsigned short*)alloc((size_t)N * 128 * 2);
  unsigned short* qb   = (unsigned short*)alloc((size_t)N * 512 * 2);
  unsigned short* kbuf = (unsigned short*)alloc((size_t)N * 512 * 2);
  unsigned short* vbuf = (unsigned short*)alloc((size_t)N * 512 * 2);
  unsigned short* BT   = (unsigned short*)alloc((size_t)3 * 1664 * 128 * 2);
  float* biascat       = (float*)alloc((size_t)3 * 1664 * 4);
  int* deg             = (int*)alloc((size_t)(N + 1) * 4);
  int* row_start       = (int*)alloc((size_t)(N + 1) * 4);
  int* cursor          = (int*)alloc((size_t)(N + 1) * 4);
  int* bsums           = (int*)alloc((size_t)1024 * 4);
  int* bsums_scan      = (int*)alloc((size_t)1024 * 4);
  int* csr_src         = (int*)alloc((size_t)E * 4);
  float* hEmb          = (float*)alloc((size_t)G * 128 * 4);
  float* tEmb          = (float*)alloc((size_t)G * 128 * 4);
  (void)ws_size; (void)n_in; (void)out_size;

  const int nScanBlocks = (N + 255) / 256;

  // Convert weights once per call (shared by both graphs)
  wcvt_kernel<<<3 * 1664, 128, 0, stream>>>(Wq, bq, Wk, bk, Wv, bv, Ws, bs, BT, biascat);

  for (int g = 0; g < 2; g++) {
    const float* x     = g ? t_x : h_x;
    const int*   ei    = g ? t_ei : h_ei;
    const int*   batch = g ? t_batch : h_batch;
    float*       emb   = g ? tEmb : hEmb;
    const int* srcp = ei;
    const int* dstp = ei + E;

    // --- build CSR (edges grouped by dst) ---
    hipMemsetAsync(deg, 0, (size_t)(N + 1) * 4, stream);
    hist_kernel<<<(E + 255) / 256, 256, 0, stream>>>(dstp, deg, E);
    scan_block_kernel<<<nScanBlocks, 256, 0, stream>>>(deg, row_start, bsums, N);
    scan_block_kernel<<<1, 256, 0, stream>>>(bsums, bsums_scan, nullptr, nScanBlocks);
    scan_finish_kernel<<<nScanBlocks, 256, 0, stream>>>(row_start, cursor, bsums_scan, N, E);
    scatter_kernel<<<(E + 255) / 256, 256, 0, stream>>>(srcp, dstp, cursor, csr_src, E);

    lin0_kernel<<<N, 128, 0, stream>>>(x, lin0_W, lin0_b, hA, hbuf, N, inF);
    for (int l = 0; l < 3; l++) {
      proj_mfma_kernel<<<(N + 127) / 128, 256, 0, stream>>>(hbuf,
          BT + (size_t)l * 1664 * 128, biascat + (size_t)l * 1664, N,
          qb, kbuf, vbuf, hA);
      node_attn_kernel<<<(N + 3) / 4, 256, 0, stream>>>(qb, kbuf, vbuf,
          row_start, csr_src, hA, hbuf, N);
    }
    hipMemsetAsync(emb, 0, (size_t)G * 128 * 4, stream);
    pool_kernel<<<(N + 127) / 128, 128, 0, stream>>>(hA, batch, emb, N);
  }

  score_kernel<<<G, 128, 0, stream>>>(hEmb, tEmb, rels, wqW, wqb, wkW, wkb,
                                      rel_emb, (float*)d_out);
}

// Round 5
// 1749.948 us; speedup vs baseline: 1.1412x; 1.1412x over previous
//
#include <hip/hip_runtime.h>
#include <math.h>

#define HID 128

typedef __attribute__((ext_vector_type(8))) short short8;
typedef __attribute__((ext_vector_type(4))) float f32x4;

__device__ __forceinline__ float bf2f(unsigned int u16) {
  union { unsigned int i; float f; } x; x.i = u16 << 16; return x.f;
}
__device__ __forceinline__ unsigned short f2bf(float f) {
  union { float f; unsigned int i; } x; x.f = f;
  unsigned int i = x.i;
  unsigned int r = i + 0x7FFFu + ((i >> 16) & 1u);
  return (unsigned short)(r >> 16);
}

// k-major panel layout for MFMA A/B sides:
//   panel p = row>>7 (128 rows), chunk J = k>>3 (8 elems), slot = J*128 + (row&127)
//   elem addr = p*16384 + slot*8 + (k&7)
// Staging a BK=32 kb-tile is then a LINEAR 8 KB copy (global_load_lds legal),
// and fragment ds_read_b128 hits 8 distinct bank-quads per phase (conflict-free).

// ---------------- weight convert: k-major panels + biascat ----------------
__global__ __launch_bounds__(128) void wcvt_kernel(
    const float* __restrict__ Wq, const float* __restrict__ bq,
    const float* __restrict__ Wk, const float* __restrict__ bk,
    const float* __restrict__ Wv, const float* __restrict__ bv,
    const float* __restrict__ Ws, const float* __restrict__ bs,
    unsigned short* __restrict__ BT, float* __restrict__ biascat)
{
  int id = blockIdx.x;
  int l = id / 1664;
  int n = id - l * 1664;
  int k = threadIdx.x;
  const float* W; const float* bias; int nl, ldb;
  if (n < 512)       { W = Wq + (size_t)l * 65536; bias = bq + (size_t)l * 512; nl = n;        ldb = 512; }
  else if (n < 1024) { W = Wk + (size_t)l * 65536; bias = bk + (size_t)l * 512; nl = n - 512;  ldb = 512; }
  else if (n < 1536) { W = Wv + (size_t)l * 65536; bias = bv + (size_t)l * 512; nl = n - 1024; ldb = 512; }
  else               { W = Ws + (size_t)l * 16384; bias = bs + (size_t)l * 128; nl = n - 1536; ldb = 128; }
  size_t dst = (size_t)l * 212992 + (size_t)(n >> 7) * 16384
             + (size_t)((k >> 3) * 128 + (n & 127)) * 8 + (k & 7);
  BT[dst] = f2bf(W[(size_t)k * ldb + nl]);
  if (k == 0) biascat[(size_t)l * 1664 + n] = bias[nl];
}

// ---------------- lin0: h = x @ W(70x128) + b (fp32 + k-major bf16) ----------
__global__ __launch_bounds__(128) void lin0_kernel(
    const float* __restrict__ x, const float* __restrict__ W,
    const float* __restrict__ b, float* __restrict__ h,
    unsigned short* __restrict__ hb, int N, int inF)
{
  __shared__ float xs[128];
  int n = blockIdx.x;
  int t = threadIdx.x;
  if (t < inF) xs[t] = x[(size_t)n * inF + t];
  __syncthreads();
  float acc = b[t];
  for (int k = 0; k < inF; k++) acc += xs[k] * W[(size_t)k * 128 + t];
  h[(size_t)n * 128 + t] = acc;
  hb[(size_t)(n >> 7) * 16384 + (size_t)((t >> 3) * 128 + (n & 127)) * 8 + (t & 7)] = f2bf(acc);
}

// ---------------- MFMA projection GEMM ----------------
// grid (ceil(M/128), 13); block 256 = 4 waves; per-wave 64x64 via 4x4 16x16 tiles.
// Operand-swapped MFMA (bf, af) -> lane's f32x4 = 4 consecutive cols of one row
// -> 8-B bf16 / 16-B fp32 epilogue stores.
__global__ __launch_bounds__(256) void proj_mfma_kernel(
    const unsigned short* __restrict__ A, const unsigned short* __restrict__ BT,
    const float* __restrict__ bias, int M,
    unsigned short* __restrict__ qo, unsigned short* __restrict__ ko,
    unsigned short* __restrict__ vo, float* __restrict__ hn)
{
  __shared__ unsigned short lsA[4096];
  __shared__ unsigned short lsB[4096];
  const int t = threadIdx.x;
  const int wv = t >> 6, ln = t & 63;
  const int wx = wv & 1, wy = wv >> 1;
  const int m0 = blockIdx.x * 128;
  const int nc = blockIdx.y;
  const int fr = ln & 15, quad = ln >> 4;

  const unsigned short* Ap = A + (size_t)blockIdx.x * 16384;
  const unsigned short* Bp = BT + (size_t)nc * 16384;

  f32x4 acc[4][4];
#pragma unroll
  for (int i = 0; i < 4; i++)
#pragma unroll
    for (int j = 0; j < 4; j++) acc[i][j] = (f32x4){0.f, 0.f, 0.f, 0.f};

  for (int kb = 0; kb < 4; kb++) {
    __syncthreads();                          // protect prev iter's ds_reads
#pragma unroll
    for (int it = 0; it < 2; it++) {
      const int c = it * 256 + t;             // 16-B chunk id, linear
      __builtin_amdgcn_global_load_lds(
          (const __attribute__((address_space(1))) void*)(Ap + (size_t)kb * 4096 + c * 8),
          (__attribute__((address_space(3))) void*)((char*)lsA + c * 16), 16, 0, 0);
      __builtin_amdgcn_global_load_lds(
          (const __attribute__((address_space(1))) void*)(Bp + (size_t)kb * 4096 + c * 8),
          (__attribute__((address_space(3))) void*)((char*)lsB + c * 16), 16, 0, 0);
    }
    __syncthreads();

    short8 af[4], bf[4];
#pragma unroll
    for (int i = 0; i < 4; i++)
      af[i] = *(const short8*)(&lsA[(size_t)(quad * 128 + wy * 64 + i * 16 + fr) * 8]);
#pragma unroll
    for (int j = 0; j < 4; j++)
      bf[j] = *(const short8*)(&lsB[(size_t)(quad * 128 + wx * 64 + j * 16 + fr) * 8]);
#pragma unroll
    for (int i = 0; i < 4; i++)
#pragma unroll
      for (int j = 0; j < 4; j++)
        acc[i][j] = __builtin_amdgcn_mfma_f32_16x16x32_bf16(bf[j], af[i], acc[i][j], 0, 0, 0);
  }

  // epilogue: lane holds rows m0+wy*64+i*16+fr, cols nc*128+wx*64+j*16+quad*4+(0..3)
  const int region = nc >> 2;                 // 0=q 1=k 2=v 3=skip
  unsigned short* out16 = (region == 0) ? qo : (region == 1) ? ko : vo;
#pragma unroll
  for (int j = 0; j < 4; j++) {
    const int colb = nc * 128 + wx * 64 + j * 16 + quad * 4;
    const float4 b4 = *(const float4*)(&bias[colb]);
    const int col = colb - region * 512;
#pragma unroll
    for (int i = 0; i < 4; i++) {
      const int row = m0 + wy * 64 + i * 16 + fr;
      if (row < M) {
        f32x4 c = acc[i][j];
        float v0 = c[0] + b4.x, v1 = c[1] + b4.y, v2 = c[2] + b4.z, v3 = c[3] + b4.w;
        if (region < 3) {
          uint2 pk;
          pk.x = (unsigned int)f2bf(v0) | ((unsigned int)f2bf(v1) << 16);
          pk.y = (unsigned int)f2bf(v2) | ((unsigned int)f2bf(v3) << 16);
          *(uint2*)(out16 + (size_t)row * 512 + col) = pk;
        } else {
          *(float4*)(hn + (size_t)row * 128 + col) = make_float4(v0, v1, v2, v3);
        }
      }
    }
  }
}

// ---------------- CSR build ----------------
__global__ __launch_bounds__(256) void hist_kernel(
    const int* __restrict__ dst, int* __restrict__ deg, int E)
{
  int e = blockIdx.x * 256 + threadIdx.x;
  if (e < E) atomicAdd(&deg[dst[e]], 1);
}

__global__ __launch_bounds__(256) void scan_block_kernel(
    const int* __restrict__ in, int* __restrict__ out, int* __restrict__ bsums, int N)
{
  __shared__ int sm[256];
  int i = blockIdx.x * 256 + threadIdx.x;
  int v = (i < N) ? in[i] : 0;
  sm[threadIdx.x] = v; __syncthreads();
  for (int off = 1; off < 256; off <<= 1) {
    int t = (threadIdx.x >= off) ? sm[threadIdx.x - off] : 0;
    __syncthreads();
    sm[threadIdx.x] += t;
    __syncthreads();
  }
  if (i < N) out[i] = sm[threadIdx.x] - v;   // exclusive
  if (threadIdx.x == 255 && bsums) bsums[blockIdx.x] = sm[255];
}

__global__ __launch_bounds__(256) void scan_finish_kernel(
    int* __restrict__ row_start, int* __restrict__ cursor,
    const int* __restrict__ bsums_scan, int N, int E)
{
  int i = blockIdx.x * 256 + threadIdx.x;
  if (i < N) {
    int val = row_start[i] + bsums_scan[blockIdx.x];
    row_start[i] = val;
    cursor[i] = val;
  }
  if (i == 0) row_start[N] = E;
}

__global__ __launch_bounds__(256) void scatter_kernel(
    const int* __restrict__ src, const int* __restrict__ dst,
    int* __restrict__ cursor, int* __restrict__ csr_src, int E)
{
  int e = blockIdx.x * 256 + threadIdx.x;
  if (e < E) {
    int pos = atomicAdd(&cursor[dst[e]], 1);
    csr_src[pos] = src[e];
  }
}

// ---------------- fused per-node attention (one wave per dst node) ----------
// h[d] = relu(h[d] + mean_h(softmax_e * v[src_e,h,:]));  hb = bf16 k-major panel
// Depth-3 software pipeline over edges (6 gathers in flight).
__global__ __launch_bounds__(256) void node_attn_kernel(
    const unsigned short* __restrict__ q, const unsigned short* __restrict__ k,
    const unsigned short* __restrict__ v,
    const int* __restrict__ row_start, const int* __restrict__ csr_src,
    float* __restrict__ hn, unsigned short* __restrict__ hb, int N)
{
  int d = (blockIdx.x * 256 + threadIdx.x) >> 6;
  int lane = threadIdx.x & 63;
  if (d >= N) return;
  int beg = row_start[d], end = row_start[d + 1];

  const uint4 qv = *(const uint4*)(q + (size_t)d * 512 + lane * 8);
  float q0 = bf2f(qv.x & 0xFFFFu), q1 = bf2f(qv.x >> 16);
  float q2 = bf2f(qv.y & 0xFFFFu), q3 = bf2f(qv.y >> 16);
  float q4 = bf2f(qv.z & 0xFFFFu), q5 = bf2f(qv.z >> 16);
  float q6 = bf2f(qv.w & 0xFFFFu), q7 = bf2f(qv.w >> 16);

  float num[8] = {0.f,0.f,0.f,0.f,0.f,0.f,0.f,0.f};
  float den = 0.f;

  auto krow = [&](int s) { return *(const uint4*)(k + (size_t)s * 512 + lane * 8); };
  auto vrow = [&](int s) { return *(const uint4*)(v + (size_t)s * 512 + lane * 8); };
  auto accum = [&](const uint4& kv, const uint4& vv) {
    float p = q0 * bf2f(kv.x & 0xFFFFu) + q1 * bf2f(kv.x >> 16)
            + q2 * bf2f(kv.y & 0xFFFFu) + q3 * bf2f(kv.y >> 16)
            + q4 * bf2f(kv.z & 0xFFFFu) + q5 * bf2f(kv.z >> 16)
            + q6 * bf2f(kv.w & 0xFFFFu) + q7 * bf2f(kv.w >> 16);
    p += __shfl_xor(p, 1);
    p += __shfl_xor(p, 2);
    p += __shfl_xor(p, 4);
    p += __shfl_xor(p, 8);
    float e = __expf(p * 0.08838834764831845f);  // 1/sqrt(128)
    den += e;
    num[0] += e * bf2f(vv.x & 0xFFFFu); num[1] += e * bf2f(vv.x >> 16);
    num[2] += e * bf2f(vv.y & 0xFFFFu); num[3] += e * bf2f(vv.y >> 16);
    num[4] += e * bf2f(vv.z & 0xFFFFu); num[5] += e * bf2f(vv.z >> 16);
    num[6] += e * bf2f(vv.w & 0xFFFFu); num[7] += e * bf2f(vv.w >> 16);
  };

  if (beg < end) {
    const int last = end - 1;
    int s0 = csr_src[beg];
    int s1 = csr_src[min(beg + 1, last)];
    int s2 = csr_src[min(beg + 2, last)];
    uint4 k0 = krow(s0), v0 = vrow(s0);
    uint4 k1 = krow(s1), v1 = vrow(s1);
    uint4 k2 = krow(s2), v2 = vrow(s2);
    for (int i = beg; i < end; i += 3) {
      int t0 = csr_src[min(i + 3, last)];
      int t1 = csr_src[min(i + 4, last)];
      int t2 = csr_src[min(i + 5, last)];
      uint4 ka = krow(t0), va = vrow(t0);
      uint4 kb = krow(t1), vb = vrow(t1);
      uint4 kc = krow(t2), vc = vrow(t2);
      accum(k0, v0);
      if (i + 1 < end) accum(k1, v1);
      if (i + 2 < end) accum(k2, v2);
      k0 = ka; v0 = va; k1 = kb; v1 = vb; k2 = kc; v2 = vc;
    }
  }

  float inv = (den > 0.f) ? 0.25f / den : 0.f;
#pragma unroll
  for (int j = 0; j < 8; j++) {
    float r = num[j] * inv;
    r += __shfl_xor(r, 16);   // combine 4 heads
    r += __shfl_xor(r, 32);
    num[j] = r;
  }
  if (lane < 16) {
    float* hp = hn + (size_t)d * 128 + lane * 8;
    float4 o0 = *(const float4*)(hp);
    float4 o1 = *(const float4*)(hp + 4);
    o0.x = fmaxf(o0.x + num[0], 0.f);
    o0.y = fmaxf(o0.y + num[1], 0.f);
    o0.z = fmaxf(o0.z + num[2], 0.f);
    o0.w = fmaxf(o0.w + num[3], 0.f);
    o1.x = fmaxf(o1.x + num[4], 0.f);
    o1.y = fmaxf(o1.y + num[5], 0.f);
    o1.z = fmaxf(o1.z + num[6], 0.f);
    o1.w = fmaxf(o1.w + num[7], 0.f);
    *(float4*)(hp) = o0;
    *(float4*)(hp + 4) = o1;
    uint4 hv;
    hv.x = (unsigned int)f2bf(o0.x) | ((unsigned int)f2bf(o0.y) << 16);
    hv.y = (unsigned int)f2bf(o0.z) | ((unsigned int)f2bf(o0.w) << 16);
    hv.z = (unsigned int)f2bf(o1.x) | ((unsigned int)f2bf(o1.y) << 16);
    hv.w = (unsigned int)f2bf(o1.z) | ((unsigned int)f2bf(o1.w) << 16);
    // k-major panel: chunk J = lane, row = d
    *(uint4*)(hb + (size_t)(d >> 7) * 16384 + (size_t)(lane * 128 + (d & 127)) * 8) = hv;
  }
}

// ---------------- pooling: emb[batch[n]] += h[n] (batch sorted) ----------------
__global__ __launch_bounds__(128) void pool_kernel(
    const float* __restrict__ h, const int* __restrict__ batch,
    float* __restrict__ emb, int N)
{
  int d = threadIdx.x;
  int n0 = blockIdx.x * 128;
  int n1 = min(n0 + 128, N);
  float acc = 0.f; int cur = -1;
  for (int n = n0; n < n1; n++) {
    int g = batch[n];
    if (g != cur) {
      if (cur >= 0) atomicAdd(&emb[(size_t)cur * 128 + d], acc);
      cur = g; acc = 0.f;
    }
    acc += h[(size_t)n * 128 + d];
  }
  if (cur >= 0) atomicAdd(&emb[(size_t)cur * 128 + d], acc);
}

// ---------------- final score ----------------
__global__ __launch_bounds__(128) void score_kernel(
    const float* __restrict__ hemb, const float* __restrict__ temb,
    const int* __restrict__ rels,
    const float* __restrict__ wqW, const float* __restrict__ wqb,
    const float* __restrict__ wkW, const float* __restrict__ wkb,
    const float* __restrict__ rel_emb, float* __restrict__ out)
{
  const int b = blockIdx.x, i = threadIdx.x;
  __shared__ float hs[128], ts[128], hnv[128], tnv[128], red[128];
  hs[i] = hemb[(size_t)b * 128 + i];
  ts[i] = temb[(size_t)b * 128 + i];
  __syncthreads();
  float qv = wqb[i], kv = wkb[i];
  for (int k = 0; k < 128; k++) {
    qv += hs[k] * wqW[k * 128 + i];
    kv += ts[k] * wkW[k * 128 + i];
  }
  float inter = tanhf(qv * kv);
  float hx = hs[i] + inter, tx2 = ts[i] + inter;

  red[i] = hx * hx; __syncthreads();
  for (int s = 64; s > 0; s >>= 1) { if (i < s) red[i] += red[i + s]; __syncthreads(); }
  float hnorm = fmaxf(sqrtf(red[0]), 1e-12f);
  __syncthreads();
  red[i] = tx2 * tx2; __syncthreads();
  for (int s = 64; s > 0; s >>= 1) { if (i < s) red[i] += red[i + s]; __syncthreads(); }
  float tnorm = fmaxf(sqrtf(red[0]), 1e-12f);
  __syncthreads();
  hnv[i] = hx / hnorm; tnv[i] = tx2 / tnorm;
  __syncthreads();

  const float* R = rel_emb + (size_t)rels[b] * 16384 + (size_t)i * 128;
  float dot = 0.f, nrm = 0.f;
  for (int j = 0; j < 128; j++) { float r = R[j]; dot += r * tnv[j]; nrm += r * r; }
  float contrib = hnv[i] * dot / fmaxf(sqrtf(nrm), 1e-12f);
  red[i] = contrib; __syncthreads();
  for (int s = 64; s > 0; s >>= 1) { if (i < s) red[i] += red[i + s]; __syncthreads(); }
  if (i == 0) out[b] = red[0];
}

extern "C" void kernel_launch(void* const* d_in, const int* in_sizes, int n_in,
                              void* d_out, int out_size, void* d_ws, size_t ws_size,
                              hipStream_t stream)
{
  const float* h_x     = (const float*)d_in[0];
  const int*   h_ei    = (const int*)d_in[1];
  const int*   h_batch = (const int*)d_in[2];
  const float* t_x     = (const float*)d_in[3];
  const int*   t_ei    = (const int*)d_in[4];
  const int*   t_batch = (const int*)d_in[5];
  const int*   rels    = (const int*)d_in[6];
  const float* lin0_W  = (const float*)d_in[7];
  const float* lin0_b  = (const float*)d_in[8];
  const float* Wq      = (const float*)d_in[9];
  const float* bq      = (const float*)d_in[10];
  const float* Wk      = (const float*)d_in[11];
  const float* bk      = (const float*)d_in[12];
  const float* Wv      = (const float*)d_in[13];
  const float* bv      = (const float*)d_in[14];
  const float* Ws      = (const float*)d_in[15];
  const float* bs      = (const float*)d_in[16];
  const float* wqW     = (const float*)d_in[17];
  const float* wqb     = (const float*)d_in[18];
  const float* wkW     = (const float*)d_in[19];
  const float* wkb     = (const float*)d_in[20];
  const float* rel_emb = (const float*)d_in[21];

  const int N = in_sizes[2];          // 50000
  const int E = in_sizes[1] / 2;      // 400000
  const int G = in_sizes[6];          // 512
  const int inF = in_sizes[7] / 128;  // 70
  const int nPanels = (N + 127) / 128;

  char* ws = (char*)d_ws;
  size_t off = 0;
  auto alloc = [&](size_t bytes) -> void* {
    void* p = ws + off; off += (bytes + 255) & ~(size_t)255; return p;
  };
  float* hA            = (float*)alloc((size_t)N * 128 * 4);
  unsigned short* hbuf = (unsigned short*)alloc((size_t)nPanels * 16384 * 2);
  unsigned short* qb   = (unsigned short*)alloc((size_t)N * 512 * 2);
  unsigned short* kbuf = (unsigned short*)alloc((size_t)N * 512 * 2);
  unsigned short* vbuf = (unsigned short*)alloc((size_t)N * 512 * 2);
  unsigned short* BT   = (unsigned short*)alloc((size_t)3 * 212992 * 2);
  float* biascat       = (float*)alloc((size_t)3 * 1664 * 4);
  int* deg             = (int*)alloc((size_t)(N + 1) * 4);
  int* row_start       = (int*)alloc((size_t)(N + 1) * 4);
  int* cursor          = (int*)alloc((size_t)(N + 1) * 4);
  int* bsums           = (int*)alloc((size_t)1024 * 4);
  int* bsums_scan      = (int*)alloc((size_t)1024 * 4);
  int* csr_src         = (int*)alloc((size_t)E * 4);
  float* hEmb          = (float*)alloc((size_t)G * 128 * 4);
  float* tEmb          = (float*)alloc((size_t)G * 128 * 4);
  (void)ws_size; (void)n_in; (void)out_size;

  const int nScanBlocks = (N + 255) / 256;

  // Convert weights once per call (shared by both graphs)
  wcvt_kernel<<<3 * 1664, 128, 0, stream>>>(Wq, bq, Wk, bk, Wv, bv, Ws, bs, BT, biascat);

  for (int g = 0; g < 2; g++) {
    const float* x     = g ? t_x : h_x;
    const int*   ei    = g ? t_ei : h_ei;
    const int*   batch = g ? t_batch : h_batch;
    float*       emb   = g ? tEmb : hEmb;
    const int* srcp = ei;
    const int* dstp = ei + E;

    // --- build CSR (edges grouped by dst) ---
    hipMemsetAsync(deg, 0, (size_t)(N + 1) * 4, stream);
    hist_kernel<<<(E + 255) / 256, 256, 0, stream>>>(dstp, deg, E);
    scan_block_kernel<<<nScanBlocks, 256, 0, stream>>>(deg, row_start, bsums, N);
    scan_block_kernel<<<1, 256, 0, stream>>>(bsums, bsums_scan, nullptr, nScanBlocks);
    scan_finish_kernel<<<nScanBlocks, 256, 0, stream>>>(row_start, cursor, bsums_scan, N, E);
    scatter_kernel<<<(E + 255) / 256, 256, 0, stream>>>(srcp, dstp, cursor, csr_src, E);

    lin0_kernel<<<N, 128, 0, stream>>>(x, lin0_W, lin0_b, hA, hbuf, N, inF);
    for (int l = 0; l < 3; l++) {
      dim3 pg(nPanels, 13);
      proj_mfma_kernel<<<pg, 256, 0, stream>>>(hbuf,
          BT + (size_t)l * 212992, biascat + (size_t)l * 1664, N,
          qb, kbuf, vbuf, hA);
      node_attn_kernel<<<(N + 3) / 4, 256, 0, stream>>>(qb, kbuf, vbuf,
          row_start, csr_src, hA, hbuf, N);
    }
    hipMemsetAsync(emb, 0, (size_t)G * 128 * 4, stream);
    pool_kernel<<<(N + 127) / 128, 128, 0, stream>>>(hA, batch, emb, N);
  }

  score_kernel<<<G, 128, 0, stream>>>(hEmb, tEmb, rels, wqW, wqb, wkW, wkb,
                                      rel_emb, (float*)d_out);
}